// Round 1
// baseline (678.997 us; speedup 1.0000x reference)
//
#include <hip/hip_runtime.h>
#include <math.h>

// Hyena filter: k = MLP(z)·decay ; out = irfft(rfft(x,8192)*rfft(k,8192))[:4096] + x*bias
// FFT strategy: rfft(8192 real) via complex FFT of N=4096 (even/odd packing),
// radix-8 Stockham (4 passes), in-place in LDS (each pass: all data in regs,
// barrier, write back). Pad LDS index by i>>3 to break stride-8 bank conflicts.

#define PAD(i) ((i) + ((i) >> 3))
#define TWO_PI 6.2831853071795864769f

typedef float2 cplx;

__device__ __forceinline__ cplx cmul(cplx a, cplx b) {
    return make_float2(a.x * b.x - a.y * b.y, a.x * b.y + a.y * b.x);
}

// 8-point DFT, natural order in/out. sgn = -1 forward, +1 inverse (no scaling).
__device__ __forceinline__ void dft8(cplx v[8], float sgn) {
    cplx t;
    t = v[1]; v[1] = v[4]; v[4] = t;   // bit-reversal
    t = v[3]; v[3] = v[6]; v[6] = t;
#pragma unroll
    for (int i = 0; i < 8; i += 2) {
        cplx a = v[i], b = v[i + 1];
        v[i]     = make_float2(a.x + b.x, a.y + b.y);
        v[i + 1] = make_float2(a.x - b.x, a.y - b.y);
    }
#pragma unroll
    for (int i = 0; i < 8; i += 4) {
        cplx a = v[i], b = v[i + 2];
        v[i]     = make_float2(a.x + b.x, a.y + b.y);
        v[i + 2] = make_float2(a.x - b.x, a.y - b.y);
        cplx c1 = v[i + 1], d = v[i + 3];
        cplx dt = make_float2(-sgn * d.y, sgn * d.x);     // * (±i)
        v[i + 1] = make_float2(c1.x + dt.x, c1.y + dt.y);
        v[i + 3] = make_float2(c1.x - dt.x, c1.y - dt.y);
    }
    const float C = 0.70710678118654752440f;
    cplx a, b, bt;
    a = v[0]; b = v[4];
    v[0] = make_float2(a.x + b.x, a.y + b.y);
    v[4] = make_float2(a.x - b.x, a.y - b.y);
    a = v[1]; b = v[5]; bt = cmul(b, make_float2(C, sgn * C));
    v[1] = make_float2(a.x + bt.x, a.y + bt.y);
    v[5] = make_float2(a.x - bt.x, a.y - bt.y);
    a = v[2]; b = v[6]; bt = make_float2(-sgn * b.y, sgn * b.x);
    v[2] = make_float2(a.x + bt.x, a.y + bt.y);
    v[6] = make_float2(a.x - bt.x, a.y - bt.y);
    a = v[3]; b = v[7]; bt = cmul(b, make_float2(-C, sgn * C));
    v[3] = make_float2(a.x + bt.x, a.y + bt.y);
    v[7] = make_float2(a.x - bt.x, a.y - bt.y);
}

// One Stockham radix-8 pass over N=4096 in LDS, in place. 512 threads, j = tid.
template <int NS>
__device__ __forceinline__ void fft_pass_ip(cplx* buf, int j, float sgn) {
    cplx v[8];
#pragma unroll
    for (int r = 0; r < 8; r++) v[r] = buf[PAD(j + (r << 9))];
    if (NS > 1) {
        int jm = j & (NS - 1);
        float ang = sgn * (TWO_PI / (float)(NS * 8)) * (float)jm;
#pragma unroll
        for (int r = 1; r < 8; r++) {
            float s, c;
            __sincosf(ang * (float)r, &s, &c);
            v[r] = cmul(v[r], make_float2(c, s));
        }
    }
    dft8(v, sgn);
    __syncthreads();                       // everyone done reading
    int jm2 = j & (NS - 1);
    int base = ((j & ~(NS - 1)) << 3) + jm2;
#pragma unroll
    for (int r = 0; r < 8; r++) buf[PAD(base + r * NS)] = v[r];
    __syncthreads();
}

// Full 4096-point FFT in LDS. Caller must __syncthreads() after writing inputs.
__device__ __forceinline__ void fft4096_ip(cplx* buf, int t, float sgn) {
    fft_pass_ip<1>(buf, t, sgn);
    fft_pass_ip<8>(buf, t, sgn);
    fft_pass_ip<64>(buf, t, sgn);
    fft_pass_ip<512>(buf, t, sgn);
}

// ---------------- Kernel 1: positional MLP -> h3 (4096 x 64) ----------------
__global__ __launch_bounds__(256) void mlp_kernel(
    const float* __restrict__ zin, const float* __restrict__ W1,
    const float* __restrict__ b1, const float* __restrict__ freq,
    const float* __restrict__ W2, const float* __restrict__ b2,
    const float* __restrict__ W3, const float* __restrict__ b3,
    float* __restrict__ h3out) {
    int l = blockIdx.x * 256 + threadIdx.x;   // grid covers exactly 4096
    float zf[5];
#pragma unroll
    for (int e = 0; e < 5; e++) zf[e] = zin[l * 5 + e];
    float h1[64], h2[64];
#pragma unroll 8
    for (int o = 0; o < 64; o++) {
        float a = b1[o];
#pragma unroll
        for (int e = 0; e < 5; e++) a += W1[o * 5 + e] * zf[e];
        h1[o] = __sinf(freq[o] * a);
    }
#pragma unroll 4
    for (int p = 0; p < 64; p++) {
        float a = b2[p];
#pragma unroll 16
        for (int o = 0; o < 64; o++) a += W2[p * 64 + o] * h1[o];
        h2[p] = __sinf(freq[p] * a);
    }
#pragma unroll 4
    for (int p = 0; p < 64; p++) {
        float a = b3[p];
#pragma unroll 16
        for (int o = 0; o < 64; o++) a += W3[p * 64 + o] * h2[o];
        h3out[l * 64 + p] = __sinf(freq[p] * a);
    }
}

// ------- Kernel 2: per-channel filter row + rfft(k,8192) -> Kf[d][0..4096] -------
// Kf stored with 1/4096 inverse-FFT scale folded in. Row stride 4104 complexes.
__global__ __launch_bounds__(512) void filter_fft_kernel(
    const float* __restrict__ h3, const float* __restrict__ W4,
    const float* __restrict__ tvec, const float* __restrict__ deltas,
    float2* __restrict__ Kf) {
    __shared__ cplx buf[4608];
    __shared__ float4 w4s[16];
    int d = blockIdx.x, t = threadIdx.x;
    if (t < 16) w4s[t] = ((const float4*)(W4 + (size_t)d * 64))[t];
    float da = fabsf(deltas[d]);
    __syncthreads();

    // each thread: k[d, 8t .. 8t+7]
    float kv[8];
#pragma unroll
    for (int q = 0; q < 8; q++) {
        int l = 8 * t + q;
        const float4* h4 = (const float4*)(h3 + (size_t)l * 64);
        float acc = 0.f;
#pragma unroll
        for (int oc = 0; oc < 16; oc++) {
            float4 hv = h4[oc];
            float4 wv = w4s[oc];
            acc += hv.x * wv.x + hv.y * wv.y + hv.z * wv.z + hv.w * wv.w;
        }
        kv[q] = acc * __expf(-tvec[l] * da);
    }
    // pack even/odd into complex, zero upper half
#pragma unroll
    for (int q = 0; q < 4; q++) {
        buf[PAD(4 * t + q)] = make_float2(kv[2 * q], kv[2 * q + 1]);
        buf[PAD(2048 + 4 * t + q)] = make_float2(0.f, 0.f);
    }
    __syncthreads();
    fft4096_ip(buf, t, -1.0f);

    const float scale = 1.0f / 4096.0f;
    float2* KfRow = Kf + (size_t)d * 4104;
#pragma unroll
    for (int i = 0; i < 4; i++) {
        int k = t + (i << 9);
        if (k == 0) {
            cplx z0 = buf[PAD(0)];
            KfRow[0]    = make_float2((z0.x + z0.y) * scale, 0.f);
            KfRow[4096] = make_float2((z0.x - z0.y) * scale, 0.f);
            cplx zm = buf[PAD(2048)];
            KfRow[2048] = make_float2(zm.x * scale, -zm.y * scale);
        } else {
            int k2 = 4096 - k;
            cplx Zk = buf[PAD(k)], Zq = buf[PAD(k2)];
            cplx Fe = make_float2(0.5f * (Zk.x + Zq.x), 0.5f * (Zk.y - Zq.y));
            cplx Fo = make_float2(0.5f * (Zk.y + Zq.y), -0.5f * (Zk.x - Zq.x));
            float s, c;
            __sincosf(-TWO_PI * (float)k * (1.0f / 8192.0f), &s, &c);
            cplx WFo = cmul(make_float2(c, s), Fo);
            KfRow[k]  = make_float2((Fe.x + WFo.x) * scale, (Fe.y + WFo.y) * scale);
            KfRow[k2] = make_float2((Fe.x - WFo.x) * scale, -(Fe.y - WFo.y) * scale);
        }
    }
}

// ------- Kernel 3: per (b,d) row: FFT -> spectral multiply -> IFFT -> +x*bias -------
__global__ __launch_bounds__(512) void conv_kernel(
    const float* __restrict__ x, const float2* __restrict__ Kf,
    const float* __restrict__ bias, float* __restrict__ out) {
    __shared__ cplx buf[4608];
    int rid = blockIdx.x;          // rid = b*1024 + d
    int d = rid & 1023;
    int t = threadIdx.x;
    const float4* x4 = (const float4*)(x + (size_t)rid * 4096);

    // load x row, pack even/odd, zero-pad upper half
#pragma unroll
    for (int i = 0; i < 2; i++) {
        int q = t + (i << 9);
        float4 v = x4[q];
        buf[PAD(2 * q)]     = make_float2(v.x, v.y);
        buf[PAD(2 * q + 1)] = make_float2(v.z, v.w);
    }
#pragma unroll
    for (int i = 2; i < 4; i++) {
        int q = t + (i << 9);
        buf[PAD(2 * q)]     = make_float2(0.f, 0.f);
        buf[PAD(2 * q + 1)] = make_float2(0.f, 0.f);
    }
    __syncthreads();
    fft4096_ip(buf, t, -1.0f);

    // spectral combine: each (k, 4096-k) pair owned by one thread -> in-place, no hazard
    const float2* KfRow = Kf + (size_t)d * 4104;
#pragma unroll
    for (int i = 0; i < 4; i++) {
        int k = t + (i << 9);
        if (k == 0) {
            cplx z0 = buf[PAD(0)];
            float U0 = z0.x + z0.y;
            float UN = z0.x - z0.y;
            float Y0 = U0 * KfRow[0].x;
            float YN = UN * KfRow[4096].x;
            buf[PAD(0)] = make_float2(0.5f * (Y0 + YN), 0.5f * (Y0 - YN));
            cplx zm = buf[PAD(2048)];
            cplx Um = make_float2(zm.x, -zm.y);          // U[2048] = conj(Z[2048])
            cplx Ym = cmul(Um, KfRow[2048]);
            buf[PAD(2048)] = make_float2(Ym.x, -Ym.y);   // Z'[2048] = conj(Y)
        } else {
            int k2 = 4096 - k;
            cplx Zk = buf[PAD(k)], Zq = buf[PAD(k2)];
            cplx K1 = KfRow[k], K2 = KfRow[k2];
            cplx Fe = make_float2(0.5f * (Zk.x + Zq.x), 0.5f * (Zk.y - Zq.y));
            cplx Fo = make_float2(0.5f * (Zk.y + Zq.y), -0.5f * (Zk.x - Zq.x));
            float s, c;
            __sincosf(-TWO_PI * (float)k * (1.0f / 8192.0f), &s, &c);
            cplx WFo = cmul(make_float2(c, s), Fo);
            cplx U1 = make_float2(Fe.x + WFo.x, Fe.y + WFo.y);
            cplx U2 = make_float2(Fe.x - WFo.x, -(Fe.y - WFo.y));  // conj(Fe - W*Fo)
            cplx Y1 = cmul(U1, K1);
            cplx Y2 = cmul(U2, K2);
            cplx FeY = make_float2(0.5f * (Y1.x + Y2.x), 0.5f * (Y1.y - Y2.y));
            cplx T   = make_float2(0.5f * (Y1.x - Y2.x), 0.5f * (Y1.y + Y2.y));
            cplx FoY = cmul(make_float2(c, -s), T);      // e^{+2πik/n} * T
            buf[PAD(k)]  = make_float2(FeY.x - FoY.y, FeY.y + FoY.x);
            buf[PAD(k2)] = make_float2(FeY.x + FoY.y, FoY.x - FeY.y);
        }
    }
    __syncthreads();
    fft4096_ip(buf, t, 1.0f);      // inverse (1/N folded into Kf)

    // y[2m] = Re z'[m], y[2m+1] = Im z'[m]; out = y + x*bias[d]
    float bd = bias[d];
    float4* o4 = (float4*)(out + (size_t)rid * 4096);
#pragma unroll
    for (int i = 0; i < 2; i++) {
        int q = t + (i << 9);
        float4 xv = x4[q];
        cplx za = buf[PAD(2 * q)], zb = buf[PAD(2 * q + 1)];
        float4 o;
        o.x = za.x + xv.x * bd;
        o.y = za.y + xv.y * bd;
        o.z = zb.x + xv.z * bd;
        o.w = zb.y + xv.w * bd;
        o4[q] = o;
    }
}

extern "C" void kernel_launch(void* const* d_in, const int* in_sizes, int n_in,
                              void* d_out, int out_size, void* d_ws, size_t ws_size,
                              hipStream_t stream) {
    const float* x      = (const float*)d_in[0];
    // d_in[1] = L (int scalar) — compile-time constant 4096 here
    const float* zin    = (const float*)d_in[2];
    const float* tvec   = (const float*)d_in[3];
    const float* deltas = (const float*)d_in[4];
    const float* W1     = (const float*)d_in[5];
    const float* b1     = (const float*)d_in[6];
    const float* freq   = (const float*)d_in[7];
    const float* W2     = (const float*)d_in[8];
    const float* b2     = (const float*)d_in[9];
    const float* W3     = (const float*)d_in[10];
    const float* b3     = (const float*)d_in[11];
    const float* W4     = (const float*)d_in[12];
    const float* bias   = (const float*)d_in[13];
    float* out = (float*)d_out;

    // workspace layout: h3 (4096*64 f32 = 1 MB) | Kf (1024 rows * 4104 cplx = 33.6 MB)
    float*  h3 = (float*)d_ws;
    float2* Kf = (float2*)((char*)d_ws + (size_t)4096 * 64 * sizeof(float));

    mlp_kernel<<<16, 256, 0, stream>>>(zin, W1, b1, freq, W2, b2, W3, b3, h3);
    filter_fft_kernel<<<1024, 512, 0, stream>>>(h3, W4, tvec, deltas, Kf);
    conv_kernel<<<4096, 512, 0, stream>>>(x, Kf, bias, out);
}

// Round 2
// 317.808 us; speedup vs baseline: 2.1365x; 2.1365x over previous
//
#include <hip/hip_runtime.h>
#include <math.h>

// Hyena filter: k = MLP(z)·decay ; out = irfft(rfft(x,8192)*rfft(k,8192))[:4096] + x*bias
// FFT: rfft(8192 real) via complex FFT of N=4096 (even/odd packing),
// radix-8 Stockham (4 passes), in-place in LDS. PAD breaks stride-8 conflicts.
// R1: mlp fully unrolled (was spilling h1/h2 to scratch -> 288us);
//     k[d,l] dot-products moved to a coalesced kgemm kernel (was 260us of
//     lane-strided h3 sweeps inside filter_fft).

#define PAD(i) ((i) + ((i) >> 3))
#define TWO_PI 6.2831853071795864769f

typedef float2 cplx;

__device__ __forceinline__ cplx cmul(cplx a, cplx b) {
    return make_float2(a.x * b.x - a.y * b.y, a.x * b.y + a.y * b.x);
}

// 8-point DFT, natural order in/out. sgn = -1 forward, +1 inverse (no scaling).
__device__ __forceinline__ void dft8(cplx v[8], float sgn) {
    cplx t;
    t = v[1]; v[1] = v[4]; v[4] = t;   // bit-reversal
    t = v[3]; v[3] = v[6]; v[6] = t;
#pragma unroll
    for (int i = 0; i < 8; i += 2) {
        cplx a = v[i], b = v[i + 1];
        v[i]     = make_float2(a.x + b.x, a.y + b.y);
        v[i + 1] = make_float2(a.x - b.x, a.y - b.y);
    }
#pragma unroll
    for (int i = 0; i < 8; i += 4) {
        cplx a = v[i], b = v[i + 2];
        v[i]     = make_float2(a.x + b.x, a.y + b.y);
        v[i + 2] = make_float2(a.x - b.x, a.y - b.y);
        cplx c1 = v[i + 1], d = v[i + 3];
        cplx dt = make_float2(-sgn * d.y, sgn * d.x);     // * (±i)
        v[i + 1] = make_float2(c1.x + dt.x, c1.y + dt.y);
        v[i + 3] = make_float2(c1.x - dt.x, c1.y - dt.y);
    }
    const float C = 0.70710678118654752440f;
    cplx a, b, bt;
    a = v[0]; b = v[4];
    v[0] = make_float2(a.x + b.x, a.y + b.y);
    v[4] = make_float2(a.x - b.x, a.y - b.y);
    a = v[1]; b = v[5]; bt = cmul(b, make_float2(C, sgn * C));
    v[1] = make_float2(a.x + bt.x, a.y + bt.y);
    v[5] = make_float2(a.x - bt.x, a.y - bt.y);
    a = v[2]; b = v[6]; bt = make_float2(-sgn * b.y, sgn * b.x);
    v[2] = make_float2(a.x + bt.x, a.y + bt.y);
    v[6] = make_float2(a.x - bt.x, a.y - bt.y);
    a = v[3]; b = v[7]; bt = cmul(b, make_float2(-C, sgn * C));
    v[3] = make_float2(a.x + bt.x, a.y + bt.y);
    v[7] = make_float2(a.x - bt.x, a.y - bt.y);
}

// One Stockham radix-8 pass over N=4096 in LDS, in place. 512 threads, j = tid.
template <int NS>
__device__ __forceinline__ void fft_pass_ip(cplx* buf, int j, float sgn) {
    cplx v[8];
#pragma unroll
    for (int r = 0; r < 8; r++) v[r] = buf[PAD(j + (r << 9))];
    if (NS > 1) {
        int jm = j & (NS - 1);
        float ang = sgn * (TWO_PI / (float)(NS * 8)) * (float)jm;
#pragma unroll
        for (int r = 1; r < 8; r++) {
            float s, c;
            __sincosf(ang * (float)r, &s, &c);
            v[r] = cmul(v[r], make_float2(c, s));
        }
    }
    dft8(v, sgn);
    __syncthreads();                       // everyone done reading
    int jm2 = j & (NS - 1);
    int base = ((j & ~(NS - 1)) << 3) + jm2;
#pragma unroll
    for (int r = 0; r < 8; r++) buf[PAD(base + r * NS)] = v[r];
    __syncthreads();
}

// Full 4096-point FFT in LDS. Caller must __syncthreads() after writing inputs.
__device__ __forceinline__ void fft4096_ip(cplx* buf, int t, float sgn) {
    fft_pass_ip<1>(buf, t, sgn);
    fft_pass_ip<8>(buf, t, sgn);
    fft_pass_ip<64>(buf, t, sgn);
    fft_pass_ip<512>(buf, t, sgn);
}

// ---------------- Kernel 1: positional MLP -> h3 (4096 x 64) ----------------
// FULLY unrolled so h1/h2 live in registers (partial unroll spilled to scratch).
__global__ __launch_bounds__(64) void mlp_kernel(
    const float* __restrict__ zin, const float* __restrict__ W1,
    const float* __restrict__ b1, const float* __restrict__ freq,
    const float* __restrict__ W2, const float* __restrict__ b2,
    const float* __restrict__ W3, const float* __restrict__ b3,
    float* __restrict__ h3out) {
    int l = blockIdx.x * 64 + threadIdx.x;   // grid = 64 blocks covers 4096
    float zf[5];
#pragma unroll
    for (int e = 0; e < 5; e++) zf[e] = zin[l * 5 + e];
    float h1[64], h2[64];
#pragma unroll
    for (int o = 0; o < 64; o++) {
        float a = b1[o];
#pragma unroll
        for (int e = 0; e < 5; e++) a += W1[o * 5 + e] * zf[e];
        h1[o] = __sinf(freq[o] * a);
    }
#pragma unroll
    for (int p = 0; p < 64; p++) {
        float a = b2[p];
#pragma unroll
        for (int o = 0; o < 64; o++) a += W2[p * 64 + o] * h1[o];
        h2[p] = __sinf(freq[p] * a);
    }
#pragma unroll
    for (int p = 0; p < 64; p++) {
        float a = b3[p];
#pragma unroll
        for (int o = 0; o < 64; o++) a += W3[p * 64 + o] * h2[o];
        h3out[l * 64 + p] = __sinf(freq[p] * a);
    }
}

// -------- Kernel 2: k[d,l] = <h3[l,:], W4[d,:]> * exp(-t[l]*|delta[d]|) --------
// Block = 64-d tile x 256-l tile. Thread <-> l (lanes contiguous => coalesced
// stores); W4 row is wave-uniform => scalarized s_loads; h3 row in registers.
__global__ __launch_bounds__(256) void kgemm_kernel(
    const float* __restrict__ h3, const float* __restrict__ W4,
    const float* __restrict__ tvec, const float* __restrict__ deltas,
    float* __restrict__ kout) {
    int lt = blockIdx.x & 15;      // l tile (16)
    int dt = blockIdx.x >> 4;      // d tile (16)
    int l = lt * 256 + threadIdx.x;
    float hreg[64];
    const float4* h4 = (const float4*)(h3 + (size_t)l * 64);
#pragma unroll
    for (int i = 0; i < 16; i++) {
        float4 v = h4[i];
        hreg[4 * i] = v.x; hreg[4 * i + 1] = v.y;
        hreg[4 * i + 2] = v.z; hreg[4 * i + 3] = v.w;
    }
    float tl = tvec[l];
    const float* W4b = W4 + (size_t)dt * 64 * 64;
    const float* db  = deltas + dt * 64;
#pragma unroll 8
    for (int d = 0; d < 64; d++) {
        float acc = 0.f;
#pragma unroll
        for (int o = 0; o < 64; o++) acc += W4b[d * 64 + o] * hreg[o];
        float dec = __expf(-tl * fabsf(db[d]));
        kout[(size_t)(dt * 64 + d) * 4096 + l] = acc * dec;
    }
}

// ------- Kernel 3: per-channel rfft(k,8192) -> Kf[d][0..4096] -------
// Kf stored with 1/4096 inverse-FFT scale folded in. Row stride 4104 complexes.
__global__ __launch_bounds__(512) void filter_fft_kernel(
    const float* __restrict__ kin, float2* __restrict__ Kf) {
    __shared__ cplx buf[4608];
    int d = blockIdx.x, t = threadIdx.x;

    // coalesced load of k row; pack even/odd into complex, zero upper half
    const float4* k4 = (const float4*)(kin + (size_t)d * 4096);
    {
        float4 f0 = k4[2 * t], f1 = k4[2 * t + 1];
        buf[PAD(4 * t + 0)] = make_float2(f0.x, f0.y);
        buf[PAD(4 * t + 1)] = make_float2(f0.z, f0.w);
        buf[PAD(4 * t + 2)] = make_float2(f1.x, f1.y);
        buf[PAD(4 * t + 3)] = make_float2(f1.z, f1.w);
#pragma unroll
        for (int q = 0; q < 4; q++)
            buf[PAD(2048 + 4 * t + q)] = make_float2(0.f, 0.f);
    }
    __syncthreads();
    fft4096_ip(buf, t, -1.0f);

    const float scale = 1.0f / 4096.0f;
    float2* KfRow = Kf + (size_t)d * 4104;
#pragma unroll
    for (int i = 0; i < 4; i++) {
        int k = t + (i << 9);
        if (k == 0) {
            cplx z0 = buf[PAD(0)];
            KfRow[0]    = make_float2((z0.x + z0.y) * scale, 0.f);
            KfRow[4096] = make_float2((z0.x - z0.y) * scale, 0.f);
            cplx zm = buf[PAD(2048)];
            KfRow[2048] = make_float2(zm.x * scale, -zm.y * scale);
        } else {
            int k2 = 4096 - k;
            cplx Zk = buf[PAD(k)], Zq = buf[PAD(k2)];
            cplx Fe = make_float2(0.5f * (Zk.x + Zq.x), 0.5f * (Zk.y - Zq.y));
            cplx Fo = make_float2(0.5f * (Zk.y + Zq.y), -0.5f * (Zk.x - Zq.x));
            float s, c;
            __sincosf(-TWO_PI * (float)k * (1.0f / 8192.0f), &s, &c);
            cplx WFo = cmul(make_float2(c, s), Fo);
            KfRow[k]  = make_float2((Fe.x + WFo.x) * scale, (Fe.y + WFo.y) * scale);
            KfRow[k2] = make_float2((Fe.x - WFo.x) * scale, -(Fe.y - WFo.y) * scale);
        }
    }
}

// ------- Kernel 4: per (b,d) row: FFT -> spectral multiply -> IFFT -> +x*bias -------
__global__ __launch_bounds__(512) void conv_kernel(
    const float* __restrict__ x, const float2* __restrict__ Kf,
    const float* __restrict__ bias, float* __restrict__ out) {
    __shared__ cplx buf[4608];
    int rid = blockIdx.x;          // rid = b*1024 + d
    int d = rid & 1023;
    int t = threadIdx.x;
    const float4* x4 = (const float4*)(x + (size_t)rid * 4096);

    // load x row, pack even/odd, zero-pad upper half
#pragma unroll
    for (int i = 0; i < 2; i++) {
        int q = t + (i << 9);
        float4 v = x4[q];
        buf[PAD(2 * q)]     = make_float2(v.x, v.y);
        buf[PAD(2 * q + 1)] = make_float2(v.z, v.w);
    }
#pragma unroll
    for (int i = 2; i < 4; i++) {
        int q = t + (i << 9);
        buf[PAD(2 * q)]     = make_float2(0.f, 0.f);
        buf[PAD(2 * q + 1)] = make_float2(0.f, 0.f);
    }
    __syncthreads();
    fft4096_ip(buf, t, -1.0f);

    // spectral combine: each (k, 4096-k) pair owned by one thread -> in-place, no hazard
    const float2* KfRow = Kf + (size_t)d * 4104;
#pragma unroll
    for (int i = 0; i < 4; i++) {
        int k = t + (i << 9);
        if (k == 0) {
            cplx z0 = buf[PAD(0)];
            float U0 = z0.x + z0.y;
            float UN = z0.x - z0.y;
            float Y0 = U0 * KfRow[0].x;
            float YN = UN * KfRow[4096].x;
            buf[PAD(0)] = make_float2(0.5f * (Y0 + YN), 0.5f * (Y0 - YN));
            cplx zm = buf[PAD(2048)];
            cplx Um = make_float2(zm.x, -zm.y);          // U[2048] = conj(Z[2048])
            cplx Ym = cmul(Um, KfRow[2048]);
            buf[PAD(2048)] = make_float2(Ym.x, -Ym.y);   // Z'[2048] = conj(Y)
        } else {
            int k2 = 4096 - k;
            cplx Zk = buf[PAD(k)], Zq = buf[PAD(k2)];
            cplx K1 = KfRow[k], K2 = KfRow[k2];
            cplx Fe = make_float2(0.5f * (Zk.x + Zq.x), 0.5f * (Zk.y - Zq.y));
            cplx Fo = make_float2(0.5f * (Zk.y + Zq.y), -0.5f * (Zk.x - Zq.x));
            float s, c;
            __sincosf(-TWO_PI * (float)k * (1.0f / 8192.0f), &s, &c);
            cplx WFo = cmul(make_float2(c, s), Fo);
            cplx U1 = make_float2(Fe.x + WFo.x, Fe.y + WFo.y);
            cplx U2 = make_float2(Fe.x - WFo.x, -(Fe.y - WFo.y));  // conj(Fe - W*Fo)
            cplx Y1 = cmul(U1, K1);
            cplx Y2 = cmul(U2, K2);
            cplx FeY = make_float2(0.5f * (Y1.x + Y2.x), 0.5f * (Y1.y - Y2.y));
            cplx T   = make_float2(0.5f * (Y1.x - Y2.x), 0.5f * (Y1.y + Y2.y));
            cplx FoY = cmul(make_float2(c, -s), T);      // e^{+2πik/n} * T
            buf[PAD(k)]  = make_float2(FeY.x - FoY.y, FeY.y + FoY.x);
            buf[PAD(k2)] = make_float2(FeY.x + FoY.y, FoY.x - FeY.y);
        }
    }
    __syncthreads();
    fft4096_ip(buf, t, 1.0f);      // inverse (1/N folded into Kf)

    // y[2m] = Re z'[m], y[2m+1] = Im z'[m]; out = y + x*bias[d]
    float bd = bias[d];
    float4* o4 = (float4*)(out + (size_t)rid * 4096);
#pragma unroll
    for (int i = 0; i < 2; i++) {
        int q = t + (i << 9);
        float4 xv = x4[q];
        cplx za = buf[PAD(2 * q)], zb = buf[PAD(2 * q + 1)];
        float4 o;
        o.x = za.x + xv.x * bd;
        o.y = za.y + xv.y * bd;
        o.z = zb.x + xv.z * bd;
        o.w = zb.y + xv.w * bd;
        o4[q] = o;
    }
}

extern "C" void kernel_launch(void* const* d_in, const int* in_sizes, int n_in,
                              void* d_out, int out_size, void* d_ws, size_t ws_size,
                              hipStream_t stream) {
    const float* x      = (const float*)d_in[0];
    // d_in[1] = L (int scalar) — compile-time constant 4096 here
    const float* zin    = (const float*)d_in[2];
    const float* tvec   = (const float*)d_in[3];
    const float* deltas = (const float*)d_in[4];
    const float* W1     = (const float*)d_in[5];
    const float* b1     = (const float*)d_in[6];
    const float* freq   = (const float*)d_in[7];
    const float* W2     = (const float*)d_in[8];
    const float* b2     = (const float*)d_in[9];
    const float* W3     = (const float*)d_in[10];
    const float* b3     = (const float*)d_in[11];
    const float* W4     = (const float*)d_in[12];
    const float* bias   = (const float*)d_in[13];
    float* out = (float*)d_out;

    // ws layout: h3 (4096*64 f32 = 1 MB) | Kf (1024 rows * 4104 cplx = 33.6 MB)
    float*  h3 = (float*)d_ws;
    float2* Kf = (float2*)((char*)d_ws + (size_t)4096 * 64 * sizeof(float));
    // k (1024x4096 f32 = 16 MB) staged in the tail of d_out (64 MB); conv
    // overwrites it afterwards (stream-ordered: kgemm -> filter_fft -> conv).
    float* kbuf = out + (size_t)3072 * 4096;

    mlp_kernel<<<64, 64, 0, stream>>>(zin, W1, b1, freq, W2, b2, W3, b3, h3);
    kgemm_kernel<<<256, 256, 0, stream>>>(h3, W4, tvec, deltas, kbuf);
    filter_fft_kernel<<<1024, 512, 0, stream>>>(kbuf, Kf);
    conv_kernel<<<4096, 512, 0, stream>>>(x, Kf, bias, out);
}

// Round 3
// 272.447 us; speedup vs baseline: 2.4922x; 1.1665x over previous
//
#include <hip/hip_runtime.h>
#include <math.h>

// Hyena filter: k = MLP(z)·decay ; out = irfft(rfft(x,8192)*rfft(k,8192))[:4096] + x*bias
// FFT: rfft(8192 real) via complex FFT of N=4096 (even/odd packing),
// radix-8 Stockham (4 passes), in-place in LDS. PAD breaks stride-8 conflicts.
// R1: coalesced kgemm; R2: mlp rewritten LDS-cooperative (256 thr = 64 l x 4
//     waves, 16 outputs/wave/layer, acts in LDS [o][l]) — the register version
//     spilled (VGPR=92 < 128 live) and had 64 waves total -> 116us of stalls.
//     h3 now stored transposed [o][l] so kgemm loads are lane-coalesced.

#define PAD(i) ((i) + ((i) >> 3))
#define TWO_PI 6.2831853071795864769f

typedef float2 cplx;

__device__ __forceinline__ cplx cmul(cplx a, cplx b) {
    return make_float2(a.x * b.x - a.y * b.y, a.x * b.y + a.y * b.x);
}

// 8-point DFT, natural order in/out. sgn = -1 forward, +1 inverse (no scaling).
__device__ __forceinline__ void dft8(cplx v[8], float sgn) {
    cplx t;
    t = v[1]; v[1] = v[4]; v[4] = t;   // bit-reversal
    t = v[3]; v[3] = v[6]; v[6] = t;
#pragma unroll
    for (int i = 0; i < 8; i += 2) {
        cplx a = v[i], b = v[i + 1];
        v[i]     = make_float2(a.x + b.x, a.y + b.y);
        v[i + 1] = make_float2(a.x - b.x, a.y - b.y);
    }
#pragma unroll
    for (int i = 0; i < 8; i += 4) {
        cplx a = v[i], b = v[i + 2];
        v[i]     = make_float2(a.x + b.x, a.y + b.y);
        v[i + 2] = make_float2(a.x - b.x, a.y - b.y);
        cplx c1 = v[i + 1], d = v[i + 3];
        cplx dt = make_float2(-sgn * d.y, sgn * d.x);     // * (±i)
        v[i + 1] = make_float2(c1.x + dt.x, c1.y + dt.y);
        v[i + 3] = make_float2(c1.x - dt.x, c1.y - dt.y);
    }
    const float C = 0.70710678118654752440f;
    cplx a, b, bt;
    a = v[0]; b = v[4];
    v[0] = make_float2(a.x + b.x, a.y + b.y);
    v[4] = make_float2(a.x - b.x, a.y - b.y);
    a = v[1]; b = v[5]; bt = cmul(b, make_float2(C, sgn * C));
    v[1] = make_float2(a.x + bt.x, a.y + bt.y);
    v[5] = make_float2(a.x - bt.x, a.y - bt.y);
    a = v[2]; b = v[6]; bt = make_float2(-sgn * b.y, sgn * b.x);
    v[2] = make_float2(a.x + bt.x, a.y + bt.y);
    v[6] = make_float2(a.x - bt.x, a.y - bt.y);
    a = v[3]; b = v[7]; bt = cmul(b, make_float2(-C, sgn * C));
    v[3] = make_float2(a.x + bt.x, a.y + bt.y);
    v[7] = make_float2(a.x - bt.x, a.y - bt.y);
}

// One Stockham radix-8 pass over N=4096 in LDS, in place. 512 threads, j = tid.
template <int NS>
__device__ __forceinline__ void fft_pass_ip(cplx* buf, int j, float sgn) {
    cplx v[8];
#pragma unroll
    for (int r = 0; r < 8; r++) v[r] = buf[PAD(j + (r << 9))];
    if (NS > 1) {
        int jm = j & (NS - 1);
        float ang = sgn * (TWO_PI / (float)(NS * 8)) * (float)jm;
#pragma unroll
        for (int r = 1; r < 8; r++) {
            float s, c;
            __sincosf(ang * (float)r, &s, &c);
            v[r] = cmul(v[r], make_float2(c, s));
        }
    }
    dft8(v, sgn);
    __syncthreads();                       // everyone done reading
    int jm2 = j & (NS - 1);
    int base = ((j & ~(NS - 1)) << 3) + jm2;
#pragma unroll
    for (int r = 0; r < 8; r++) buf[PAD(base + r * NS)] = v[r];
    __syncthreads();
}

// Full 4096-point FFT in LDS. Caller must __syncthreads() after writing inputs.
__device__ __forceinline__ void fft4096_ip(cplx* buf, int t, float sgn) {
    fft_pass_ip<1>(buf, t, sgn);
    fft_pass_ip<8>(buf, t, sgn);
    fft_pass_ip<64>(buf, t, sgn);
    fft_pass_ip<512>(buf, t, sgn);
}

// ---------------- Kernel 1: positional MLP -> h3T (64 x 4096) ----------------
// Block = 256 threads = 64 l-lanes x 4 waves; wave w owns outputs [16w,16w+16)
// of every layer. Activations staged in LDS transposed [o][l] (bank = l%32,
// 2-way = free). Per-thread regs: 16 accumulators -> no spill. Weights are
// wave-uniform -> scalar loads.
__global__ __launch_bounds__(256) void mlp_kernel(
    const float* __restrict__ zin, const float* __restrict__ W1,
    const float* __restrict__ b1, const float* __restrict__ freq,
    const float* __restrict__ W2, const float* __restrict__ b2,
    const float* __restrict__ W3, const float* __restrict__ b3,
    float* __restrict__ h3T) {
    __shared__ float hs1[64][64];
    __shared__ float hs2[64][64];
    int tid = threadIdx.x;
    int l = tid & 63, w = tid >> 6;
    int lg = blockIdx.x * 64 + l;          // grid = 64 blocks covers 4096

    float zf[5];
#pragma unroll
    for (int e = 0; e < 5; e++) zf[e] = zin[lg * 5 + e];

    // layer 1
#pragma unroll
    for (int i = 0; i < 16; i++) {
        int o = w * 16 + i;
        float a = b1[o];
#pragma unroll
        for (int e = 0; e < 5; e++) a += W1[o * 5 + e] * zf[e];
        hs1[o][l] = __sinf(freq[o] * a);
    }
    __syncthreads();

    // layer 2
    float acc[16];
#pragma unroll
    for (int i = 0; i < 16; i++) acc[i] = b2[w * 16 + i];
#pragma unroll 8
    for (int o = 0; o < 64; o++) {
        float hv = hs1[o][l];
#pragma unroll
        for (int i = 0; i < 16; i++) acc[i] += W2[(w * 16 + i) * 64 + o] * hv;
    }
#pragma unroll
    for (int i = 0; i < 16; i++)
        hs2[w * 16 + i][l] = __sinf(freq[w * 16 + i] * acc[i]);
    __syncthreads();

    // layer 3
#pragma unroll
    for (int i = 0; i < 16; i++) acc[i] = b3[w * 16 + i];
#pragma unroll 8
    for (int o = 0; o < 64; o++) {
        float hv = hs2[o][l];
#pragma unroll
        for (int i = 0; i < 16; i++) acc[i] += W3[(w * 16 + i) * 64 + o] * hv;
    }
#pragma unroll
    for (int i = 0; i < 16; i++)
        h3T[(size_t)(w * 16 + i) * 4096 + lg] = __sinf(freq[w * 16 + i] * acc[i]);
}

// -------- Kernel 2: k[d,l] = <h3[:,l], W4[d,:]> * exp(-t[l]*|delta[d]|) --------
// Block = 64-d tile x 256-l tile. Thread <-> l; h3T reads lane-coalesced;
// W4 row is wave-uniform => scalarized s_loads.
__global__ __launch_bounds__(256) void kgemm_kernel(
    const float* __restrict__ h3T, const float* __restrict__ W4,
    const float* __restrict__ tvec, const float* __restrict__ deltas,
    float* __restrict__ kout) {
    int lt = blockIdx.x & 15;      // l tile (16)
    int dt = blockIdx.x >> 4;      // d tile (16)
    int l = lt * 256 + threadIdx.x;
    float hreg[64];
#pragma unroll
    for (int o = 0; o < 64; o++) hreg[o] = h3T[(size_t)o * 4096 + l];
    float tl = tvec[l];
    const float* W4b = W4 + (size_t)dt * 64 * 64;
    const float* db  = deltas + dt * 64;
#pragma unroll 8
    for (int d = 0; d < 64; d++) {
        float acc = 0.f;
#pragma unroll
        for (int o = 0; o < 64; o++) acc += W4b[d * 64 + o] * hreg[o];
        float dec = __expf(-tl * fabsf(db[d]));
        kout[(size_t)(dt * 64 + d) * 4096 + l] = acc * dec;
    }
}

// ------- Kernel 3: per-channel rfft(k,8192) -> Kf[d][0..4096] -------
// Kf stored with 1/4096 inverse-FFT scale folded in. Row stride 4104 complexes.
__global__ __launch_bounds__(512) void filter_fft_kernel(
    const float* __restrict__ kin, float2* __restrict__ Kf) {
    __shared__ cplx buf[4608];
    int d = blockIdx.x, t = threadIdx.x;

    // coalesced load of k row; pack even/odd into complex, zero upper half
    const float4* k4 = (const float4*)(kin + (size_t)d * 4096);
    {
        float4 f0 = k4[2 * t], f1 = k4[2 * t + 1];
        buf[PAD(4 * t + 0)] = make_float2(f0.x, f0.y);
        buf[PAD(4 * t + 1)] = make_float2(f0.z, f0.w);
        buf[PAD(4 * t + 2)] = make_float2(f1.x, f1.y);
        buf[PAD(4 * t + 3)] = make_float2(f1.z, f1.w);
#pragma unroll
        for (int q = 0; q < 4; q++)
            buf[PAD(2048 + 4 * t + q)] = make_float2(0.f, 0.f);
    }
    __syncthreads();
    fft4096_ip(buf, t, -1.0f);

    const float scale = 1.0f / 4096.0f;
    float2* KfRow = Kf + (size_t)d * 4104;
#pragma unroll
    for (int i = 0; i < 4; i++) {
        int k = t + (i << 9);
        if (k == 0) {
            cplx z0 = buf[PAD(0)];
            KfRow[0]    = make_float2((z0.x + z0.y) * scale, 0.f);
            KfRow[4096] = make_float2((z0.x - z0.y) * scale, 0.f);
            cplx zm = buf[PAD(2048)];
            KfRow[2048] = make_float2(zm.x * scale, -zm.y * scale);
        } else {
            int k2 = 4096 - k;
            cplx Zk = buf[PAD(k)], Zq = buf[PAD(k2)];
            cplx Fe = make_float2(0.5f * (Zk.x + Zq.x), 0.5f * (Zk.y - Zq.y));
            cplx Fo = make_float2(0.5f * (Zk.y + Zq.y), -0.5f * (Zk.x - Zq.x));
            float s, c;
            __sincosf(-TWO_PI * (float)k * (1.0f / 8192.0f), &s, &c);
            cplx WFo = cmul(make_float2(c, s), Fo);
            KfRow[k]  = make_float2((Fe.x + WFo.x) * scale, (Fe.y + WFo.y) * scale);
            KfRow[k2] = make_float2((Fe.x - WFo.x) * scale, -(Fe.y - WFo.y) * scale);
        }
    }
}

// ------- Kernel 4: per (b,d) row: FFT -> spectral multiply -> IFFT -> +x*bias -------
__global__ __launch_bounds__(512) void conv_kernel(
    const float* __restrict__ x, const float2* __restrict__ Kf,
    const float* __restrict__ bias, float* __restrict__ out) {
    __shared__ cplx buf[4608];
    int rid = blockIdx.x;          // rid = b*1024 + d
    int d = rid & 1023;
    int t = threadIdx.x;
    const float4* x4 = (const float4*)(x + (size_t)rid * 4096);

    // load x row, pack even/odd, zero-pad upper half
#pragma unroll
    for (int i = 0; i < 2; i++) {
        int q = t + (i << 9);
        float4 v = x4[q];
        buf[PAD(2 * q)]     = make_float2(v.x, v.y);
        buf[PAD(2 * q + 1)] = make_float2(v.z, v.w);
    }
#pragma unroll
    for (int i = 2; i < 4; i++) {
        int q = t + (i << 9);
        buf[PAD(2 * q)]     = make_float2(0.f, 0.f);
        buf[PAD(2 * q + 1)] = make_float2(0.f, 0.f);
    }
    __syncthreads();
    fft4096_ip(buf, t, -1.0f);

    // spectral combine: each (k, 4096-k) pair owned by one thread -> in-place, no hazard
    const float2* KfRow = Kf + (size_t)d * 4104;
#pragma unroll
    for (int i = 0; i < 4; i++) {
        int k = t + (i << 9);
        if (k == 0) {
            cplx z0 = buf[PAD(0)];
            float U0 = z0.x + z0.y;
            float UN = z0.x - z0.y;
            float Y0 = U0 * KfRow[0].x;
            float YN = UN * KfRow[4096].x;
            buf[PAD(0)] = make_float2(0.5f * (Y0 + YN), 0.5f * (Y0 - YN));
            cplx zm = buf[PAD(2048)];
            cplx Um = make_float2(zm.x, -zm.y);          // U[2048] = conj(Z[2048])
            cplx Ym = cmul(Um, KfRow[2048]);
            buf[PAD(2048)] = make_float2(Ym.x, -Ym.y);   // Z'[2048] = conj(Y)
        } else {
            int k2 = 4096 - k;
            cplx Zk = buf[PAD(k)], Zq = buf[PAD(k2)];
            cplx K1 = KfRow[k], K2 = KfRow[k2];
            cplx Fe = make_float2(0.5f * (Zk.x + Zq.x), 0.5f * (Zk.y - Zq.y));
            cplx Fo = make_float2(0.5f * (Zk.y + Zq.y), -0.5f * (Zk.x - Zq.x));
            float s, c;
            __sincosf(-TWO_PI * (float)k * (1.0f / 8192.0f), &s, &c);
            cplx WFo = cmul(make_float2(c, s), Fo);
            cplx U1 = make_float2(Fe.x + WFo.x, Fe.y + WFo.y);
            cplx U2 = make_float2(Fe.x - WFo.x, -(Fe.y - WFo.y));  // conj(Fe - W*Fo)
            cplx Y1 = cmul(U1, K1);
            cplx Y2 = cmul(U2, K2);
            cplx FeY = make_float2(0.5f * (Y1.x + Y2.x), 0.5f * (Y1.y - Y2.y));
            cplx T   = make_float2(0.5f * (Y1.x - Y2.x), 0.5f * (Y1.y + Y2.y));
            cplx FoY = cmul(make_float2(c, -s), T);      // e^{+2πik/n} * T
            buf[PAD(k)]  = make_float2(FeY.x - FoY.y, FeY.y + FoY.x);
            buf[PAD(k2)] = make_float2(FeY.x + FoY.y, FoY.x - FeY.y);
        }
    }
    __syncthreads();
    fft4096_ip(buf, t, 1.0f);      // inverse (1/N folded into Kf)

    // y[2m] = Re z'[m], y[2m+1] = Im z'[m]; out = y + x*bias[d]
    float bd = bias[d];
    float4* o4 = (float4*)(out + (size_t)rid * 4096);
#pragma unroll
    for (int i = 0; i < 2; i++) {
        int q = t + (i << 9);
        float4 xv = x4[q];
        cplx za = buf[PAD(2 * q)], zb = buf[PAD(2 * q + 1)];
        float4 o;
        o.x = za.x + xv.x * bd;
        o.y = za.y + xv.y * bd;
        o.z = zb.x + xv.z * bd;
        o.w = zb.y + xv.w * bd;
        o4[q] = o;
    }
}

extern "C" void kernel_launch(void* const* d_in, const int* in_sizes, int n_in,
                              void* d_out, int out_size, void* d_ws, size_t ws_size,
                              hipStream_t stream) {
    const float* x      = (const float*)d_in[0];
    // d_in[1] = L (int scalar) — compile-time constant 4096 here
    const float* zin    = (const float*)d_in[2];
    const float* tvec   = (const float*)d_in[3];
    const float* deltas = (const float*)d_in[4];
    const float* W1     = (const float*)d_in[5];
    const float* b1     = (const float*)d_in[6];
    const float* freq   = (const float*)d_in[7];
    const float* W2     = (const float*)d_in[8];
    const float* b2     = (const float*)d_in[9];
    const float* W3     = (const float*)d_in[10];
    const float* b3     = (const float*)d_in[11];
    const float* W4     = (const float*)d_in[12];
    const float* bias   = (const float*)d_in[13];
    float* out = (float*)d_out;

    // ws layout: h3T (64 x 4096 f32 = 1 MB) | Kf (1024 rows * 4104 cplx = 33.6 MB)
    float*  h3T = (float*)d_ws;
    float2* Kf  = (float2*)((char*)d_ws + (size_t)64 * 4096 * sizeof(float));
    // k (1024x4096 f32 = 16 MB) staged in the tail of d_out (64 MB); conv
    // overwrites it afterwards (stream-ordered: kgemm -> filter_fft -> conv).
    float* kbuf = out + (size_t)3072 * 4096;

    mlp_kernel<<<64, 256, 0, stream>>>(zin, W1, b1, freq, W2, b2, W3, b3, h3T);
    kgemm_kernel<<<256, 256, 0, stream>>>(h3T, W4, tvec, deltas, kbuf);
    filter_fft_kernel<<<1024, 512, 0, stream>>>(kbuf, Kf);
    conv_kernel<<<4096, 512, 0, stream>>>(x, Kf, bias, out);
}

// Round 4
// 245.005 us; speedup vs baseline: 2.7714x; 1.1120x over previous
//
#include <hip/hip_runtime.h>
#include <math.h>

// Hyena filter: k = MLP(z)·decay ; out = irfft(rfft(x,8192)*rfft(k,8192))[:4096] + x*bias
// FFT: rfft(8192 real) via complex FFT of N=4096 (even/odd packing),
// radix-8 Stockham (4 passes), in-place in LDS. PAD breaks stride-8 conflicts.
// R3: conv/filter fuse FFT pass 1 with the global load (coalesced float2,
//     upper half known-zero) and conv fuses inverse last pass with the global
//     store (only lower half needed); x held in regs across the kernel so it
//     is fetched once. kgemm: 4 l x 16 d per thread, float4 loads/stores.

#define PAD(i) ((i) + ((i) >> 3))
#define TWO_PI 6.2831853071795864769f

typedef float2 cplx;

__device__ __forceinline__ cplx cmul(cplx a, cplx b) {
    return make_float2(a.x * b.x - a.y * b.y, a.x * b.y + a.y * b.x);
}

// 8-point DFT, natural order in/out. sgn = -1 forward, +1 inverse (no scaling).
__device__ __forceinline__ void dft8(cplx v[8], float sgn) {
    cplx t;
    t = v[1]; v[1] = v[4]; v[4] = t;   // bit-reversal
    t = v[3]; v[3] = v[6]; v[6] = t;
#pragma unroll
    for (int i = 0; i < 8; i += 2) {
        cplx a = v[i], b = v[i + 1];
        v[i]     = make_float2(a.x + b.x, a.y + b.y);
        v[i + 1] = make_float2(a.x - b.x, a.y - b.y);
    }
#pragma unroll
    for (int i = 0; i < 8; i += 4) {
        cplx a = v[i], b = v[i + 2];
        v[i]     = make_float2(a.x + b.x, a.y + b.y);
        v[i + 2] = make_float2(a.x - b.x, a.y - b.y);
        cplx c1 = v[i + 1], d = v[i + 3];
        cplx dt = make_float2(-sgn * d.y, sgn * d.x);     // * (±i)
        v[i + 1] = make_float2(c1.x + dt.x, c1.y + dt.y);
        v[i + 3] = make_float2(c1.x - dt.x, c1.y - dt.y);
    }
    const float C = 0.70710678118654752440f;
    cplx a, b, bt;
    a = v[0]; b = v[4];
    v[0] = make_float2(a.x + b.x, a.y + b.y);
    v[4] = make_float2(a.x - b.x, a.y - b.y);
    a = v[1]; b = v[5]; bt = cmul(b, make_float2(C, sgn * C));
    v[1] = make_float2(a.x + bt.x, a.y + bt.y);
    v[5] = make_float2(a.x - bt.x, a.y - bt.y);
    a = v[2]; b = v[6]; bt = make_float2(-sgn * b.y, sgn * b.x);
    v[2] = make_float2(a.x + bt.x, a.y + bt.y);
    v[6] = make_float2(a.x - bt.x, a.y - bt.y);
    a = v[3]; b = v[7]; bt = cmul(b, make_float2(-C, sgn * C));
    v[3] = make_float2(a.x + bt.x, a.y + bt.y);
    v[7] = make_float2(a.x - bt.x, a.y - bt.y);
}

// One Stockham radix-8 pass over N=4096 in LDS, in place. 512 threads, j = tid.
template <int NS>
__device__ __forceinline__ void fft_pass_ip(cplx* buf, int j, float sgn) {
    cplx v[8];
#pragma unroll
    for (int r = 0; r < 8; r++) v[r] = buf[PAD(j + (r << 9))];
    if (NS > 1) {
        int jm = j & (NS - 1);
        float ang = sgn * (TWO_PI / (float)(NS * 8)) * (float)jm;
#pragma unroll
        for (int r = 1; r < 8; r++) {
            float s, c;
            __sincosf(ang * (float)r, &s, &c);
            v[r] = cmul(v[r], make_float2(c, s));
        }
    }
    dft8(v, sgn);
    __syncthreads();                       // everyone done reading
    int jm2 = j & (NS - 1);
    int base = ((j & ~(NS - 1)) << 3) + jm2;
#pragma unroll
    for (int r = 0; r < 8; r++) buf[PAD(base + r * NS)] = v[r];
    __syncthreads();
}

// Forward FFT pass 1 (NS=1) taking inputs from registers (xv = lower half,
// upper half implicit zero). Writes PAD(8j+r) like fft_pass_ip<1>.
__device__ __forceinline__ void fft_pass1_fwd_regs(cplx* buf, int j, const cplx xv[4]) {
    cplx v[8];
#pragma unroll
    for (int r = 0; r < 4; r++) v[r] = xv[r];
#pragma unroll
    for (int r = 4; r < 8; r++) v[r] = make_float2(0.f, 0.f);
    dft8(v, -1.0f);
#pragma unroll
    for (int r = 0; r < 8; r++) buf[PAD(8 * j + r)] = v[r];
    __syncthreads();
}

// ---------------- Kernel 1: positional MLP -> h3T (64 x 4096) ----------------
// Block = 256 threads = 64 l-lanes x 4 waves; wave w owns outputs [16w,16w+16)
// of every layer. Activations staged in LDS transposed [o][l].
__global__ __launch_bounds__(256) void mlp_kernel(
    const float* __restrict__ zin, const float* __restrict__ W1,
    const float* __restrict__ b1, const float* __restrict__ freq,
    const float* __restrict__ W2, const float* __restrict__ b2,
    const float* __restrict__ W3, const float* __restrict__ b3,
    float* __restrict__ h3T) {
    __shared__ float hs1[64][64];
    __shared__ float hs2[64][64];
    int tid = threadIdx.x;
    int l = tid & 63, w = tid >> 6;
    int lg = blockIdx.x * 64 + l;          // grid = 64 blocks covers 4096

    float zf[5];
#pragma unroll
    for (int e = 0; e < 5; e++) zf[e] = zin[lg * 5 + e];

    // layer 1
#pragma unroll
    for (int i = 0; i < 16; i++) {
        int o = w * 16 + i;
        float a = b1[o];
#pragma unroll
        for (int e = 0; e < 5; e++) a += W1[o * 5 + e] * zf[e];
        hs1[o][l] = __sinf(freq[o] * a);
    }
    __syncthreads();

    // layer 2
    float acc[16];
#pragma unroll
    for (int i = 0; i < 16; i++) acc[i] = b2[w * 16 + i];
#pragma unroll 8
    for (int o = 0; o < 64; o++) {
        float hv = hs1[o][l];
#pragma unroll
        for (int i = 0; i < 16; i++) acc[i] += W2[(w * 16 + i) * 64 + o] * hv;
    }
#pragma unroll
    for (int i = 0; i < 16; i++)
        hs2[w * 16 + i][l] = __sinf(freq[w * 16 + i] * acc[i]);
    __syncthreads();

    // layer 3
#pragma unroll
    for (int i = 0; i < 16; i++) acc[i] = b3[w * 16 + i];
#pragma unroll 8
    for (int o = 0; o < 64; o++) {
        float hv = hs2[o][l];
#pragma unroll
        for (int i = 0; i < 16; i++) acc[i] += W3[(w * 16 + i) * 64 + o] * hv;
    }
#pragma unroll
    for (int i = 0; i < 16; i++)
        h3T[(size_t)(w * 16 + i) * 4096 + lg] = __sinf(freq[w * 16 + i] * acc[i]);
}

// -------- Kernel 2: k[d,l] = <h3[:,l], W4[d,:]> * exp(-t[l]*|delta[d]|) --------
// Thread owns 4 contiguous l (float4) x 16 d. Grid = 4 l-tiles x 64 d-tiles.
__global__ __launch_bounds__(256) void kgemm_kernel(
    const float* __restrict__ h3T, const float* __restrict__ W4,
    const float* __restrict__ tvec, const float* __restrict__ deltas,
    float* __restrict__ kout) {
    int lt = blockIdx.x & 3;       // l tile (4 x 1024)
    int dt = blockIdx.x >> 2;      // d tile (64 x 16)
    int l0 = lt * 1024 + threadIdx.x * 4;
    float4 acc[16];
#pragma unroll
    for (int i = 0; i < 16; i++) acc[i] = make_float4(0.f, 0.f, 0.f, 0.f);
#pragma unroll 8
    for (int o = 0; o < 64; o++) {
        float4 h = *(const float4*)(h3T + (size_t)o * 4096 + l0);
#pragma unroll
        for (int i = 0; i < 16; i++) {
            float wv = W4[(size_t)(dt * 16 + i) * 64 + o];
            acc[i].x += wv * h.x; acc[i].y += wv * h.y;
            acc[i].z += wv * h.z; acc[i].w += wv * h.w;
        }
    }
    float4 tl = *(const float4*)(tvec + l0);
#pragma unroll
    for (int i = 0; i < 16; i++) {
        int d = dt * 16 + i;
        float da = fabsf(deltas[d]);
        float4 o;
        o.x = acc[i].x * __expf(-tl.x * da);
        o.y = acc[i].y * __expf(-tl.y * da);
        o.z = acc[i].z * __expf(-tl.z * da);
        o.w = acc[i].w * __expf(-tl.w * da);
        *(float4*)(kout + (size_t)d * 4096 + l0) = o;
    }
}

// ------- Kernel 3: per-channel rfft(k,8192) -> Kf[d][0..4096] -------
// Kf stored with 1/4096 inverse-FFT scale folded in. Row stride 4104 complexes.
__global__ __launch_bounds__(512) void filter_fft_kernel(
    const float* __restrict__ kin, float2* __restrict__ Kf) {
    __shared__ cplx buf[4608];
    int d = blockIdx.x, t = threadIdx.x;

    // fwd pass 1 directly from global (pairs at m = t + r*512, r<4; rest zero)
    const cplx* k2 = (const cplx*)(kin + (size_t)d * 4096);
    cplx xv[4];
#pragma unroll
    for (int r = 0; r < 4; r++) xv[r] = k2[t + (r << 9)];
    fft_pass1_fwd_regs(buf, t, xv);
    fft_pass_ip<8>(buf, t, -1.0f);
    fft_pass_ip<64>(buf, t, -1.0f);
    fft_pass_ip<512>(buf, t, -1.0f);

    const float scale = 1.0f / 4096.0f;
    float2* KfRow = Kf + (size_t)d * 4104;
#pragma unroll
    for (int i = 0; i < 4; i++) {
        int k = t + (i << 9);
        if (k == 0) {
            cplx z0 = buf[PAD(0)];
            KfRow[0]    = make_float2((z0.x + z0.y) * scale, 0.f);
            KfRow[4096] = make_float2((z0.x - z0.y) * scale, 0.f);
            cplx zm = buf[PAD(2048)];
            KfRow[2048] = make_float2(zm.x * scale, -zm.y * scale);
        } else {
            int k2i = 4096 - k;
            cplx Zk = buf[PAD(k)], Zq = buf[PAD(k2i)];
            cplx Fe = make_float2(0.5f * (Zk.x + Zq.x), 0.5f * (Zk.y - Zq.y));
            cplx Fo = make_float2(0.5f * (Zk.y + Zq.y), -0.5f * (Zk.x - Zq.x));
            float s, c;
            __sincosf(-TWO_PI * (float)k * (1.0f / 8192.0f), &s, &c);
            cplx WFo = cmul(make_float2(c, s), Fo);
            KfRow[k]   = make_float2((Fe.x + WFo.x) * scale, (Fe.y + WFo.y) * scale);
            KfRow[k2i] = make_float2((Fe.x - WFo.x) * scale, -(Fe.y - WFo.y) * scale);
        }
    }
}

// ------- Kernel 4: per (b,d) row: FFT -> spectral multiply -> IFFT -> +x*bias -------
__global__ __launch_bounds__(512) void conv_kernel(
    const float* __restrict__ x, const float2* __restrict__ Kf,
    const float* __restrict__ bias, float* __restrict__ out) {
    __shared__ cplx buf[4608];
    int rid = blockIdx.x;          // rid = b*1024 + d
    int d = rid & 1023;
    int t = threadIdx.x;

    // fwd pass 1 directly from global; keep x pairs in regs for the epilogue
    const cplx* x2 = (const cplx*)(x + (size_t)rid * 4096);
    cplx xv[4];
#pragma unroll
    for (int r = 0; r < 4; r++) xv[r] = x2[t + (r << 9)];
    fft_pass1_fwd_regs(buf, t, xv);
    fft_pass_ip<8>(buf, t, -1.0f);
    fft_pass_ip<64>(buf, t, -1.0f);
    fft_pass_ip<512>(buf, t, -1.0f);

    // spectral combine: each (k, 4096-k) pair owned by one thread -> in-place
    const float2* KfRow = Kf + (size_t)d * 4104;
#pragma unroll
    for (int i = 0; i < 4; i++) {
        int k = t + (i << 9);
        if (k == 0) {
            cplx z0 = buf[PAD(0)];
            float U0 = z0.x + z0.y;
            float UN = z0.x - z0.y;
            float Y0 = U0 * KfRow[0].x;
            float YN = UN * KfRow[4096].x;
            buf[PAD(0)] = make_float2(0.5f * (Y0 + YN), 0.5f * (Y0 - YN));
            cplx zm = buf[PAD(2048)];
            cplx Um = make_float2(zm.x, -zm.y);          // U[2048] = conj(Z[2048])
            cplx Ym = cmul(Um, KfRow[2048]);
            buf[PAD(2048)] = make_float2(Ym.x, -Ym.y);   // Z'[2048] = conj(Y)
        } else {
            int k2i = 4096 - k;
            cplx Zk = buf[PAD(k)], Zq = buf[PAD(k2i)];
            cplx K1 = KfRow[k], K2 = KfRow[k2i];
            cplx Fe = make_float2(0.5f * (Zk.x + Zq.x), 0.5f * (Zk.y - Zq.y));
            cplx Fo = make_float2(0.5f * (Zk.y + Zq.y), -0.5f * (Zk.x - Zq.x));
            float s, c;
            __sincosf(-TWO_PI * (float)k * (1.0f / 8192.0f), &s, &c);
            cplx WFo = cmul(make_float2(c, s), Fo);
            cplx U1 = make_float2(Fe.x + WFo.x, Fe.y + WFo.y);
            cplx U2 = make_float2(Fe.x - WFo.x, -(Fe.y - WFo.y));  // conj(Fe - W*Fo)
            cplx Y1 = cmul(U1, K1);
            cplx Y2 = cmul(U2, K2);
            cplx FeY = make_float2(0.5f * (Y1.x + Y2.x), 0.5f * (Y1.y - Y2.y));
            cplx T   = make_float2(0.5f * (Y1.x - Y2.x), 0.5f * (Y1.y + Y2.y));
            cplx FoY = cmul(make_float2(c, -s), T);      // e^{+2πik/n} * T
            buf[PAD(k)]   = make_float2(FeY.x - FoY.y, FeY.y + FoY.x);
            buf[PAD(k2i)] = make_float2(FeY.x + FoY.y, FoY.x - FeY.y);
        }
    }
    __syncthreads();

    // inverse FFT; last pass fused with the global store (only m<2048 needed)
    fft_pass_ip<1>(buf, t, 1.0f);
    fft_pass_ip<8>(buf, t, 1.0f);
    fft_pass_ip<64>(buf, t, 1.0f);
    {
        cplx v[8];
#pragma unroll
        for (int r = 0; r < 8; r++) v[r] = buf[PAD(t + (r << 9))];
        float ang = (TWO_PI / 4096.0f) * (float)t;       // sgn=+1, NS=512
#pragma unroll
        for (int r = 1; r < 8; r++) {
            float s, c;
            __sincosf(ang * (float)r, &s, &c);
            v[r] = cmul(v[r], make_float2(c, s));
        }
        dft8(v, 1.0f);
        float bd = bias[d];
        cplx* o2 = (cplx*)(out + (size_t)rid * 4096);
#pragma unroll
        for (int r = 0; r < 4; r++) {                    // m = t + r*512 < 2048
            int m = t + (r << 9);
            cplx o;
            o.x = v[r].x + xv[r].x * bd;
            o.y = v[r].y + xv[r].y * bd;
            o2[m] = o;
        }
    }
}

extern "C" void kernel_launch(void* const* d_in, const int* in_sizes, int n_in,
                              void* d_out, int out_size, void* d_ws, size_t ws_size,
                              hipStream_t stream) {
    const float* x      = (const float*)d_in[0];
    // d_in[1] = L (int scalar) — compile-time constant 4096 here
    const float* zin    = (const float*)d_in[2];
    const float* tvec   = (const float*)d_in[3];
    const float* deltas = (const float*)d_in[4];
    const float* W1     = (const float*)d_in[5];
    const float* b1     = (const float*)d_in[6];
    const float* freq   = (const float*)d_in[7];
    const float* W2     = (const float*)d_in[8];
    const float* b2     = (const float*)d_in[9];
    const float* W3     = (const float*)d_in[10];
    const float* b3     = (const float*)d_in[11];
    const float* W4     = (const float*)d_in[12];
    const float* bias   = (const float*)d_in[13];
    float* out = (float*)d_out;

    // ws layout: h3T (64 x 4096 f32 = 1 MB) | Kf (1024 rows * 4104 cplx = 33.6 MB)
    float*  h3T = (float*)d_ws;
    float2* Kf  = (float2*)((char*)d_ws + (size_t)64 * 4096 * sizeof(float));
    // k (1024x4096 f32 = 16 MB) staged in the tail of d_out (64 MB); conv
    // overwrites it afterwards (stream-ordered: kgemm -> filter_fft -> conv).
    float* kbuf = out + (size_t)3072 * 4096;

    mlp_kernel<<<64, 256, 0, stream>>>(zin, W1, b1, freq, W2, b2, W3, b3, h3T);
    kgemm_kernel<<<256, 256, 0, stream>>>(h3T, W4, tvec, deltas, kbuf);
    filter_fft_kernel<<<1024, 512, 0, stream>>>(kbuf, Kf);
    conv_kernel<<<4096, 512, 0, stream>>>(x, Kf, bias, out);
}